// Round 13
// baseline (236.043 us; speedup 1.0000x reference)
//
#include <hip/hip_runtime.h>
#include <hip/hip_fp16.h>

// InstantNGP hash-grid encoding, fp32 in/out.
// N_POINTS=1048576, N_LEVELS=16, F=2. SIZES[l]=2^(l+1), OFFS[l]=2^(l+1)-2.
// Hash: h = x*(P1*P2*P3) + y*(P2*P3) + z*P3 (mod 2^32).
//
// Plateau ~121-124us across: VALU +-45%, barriers 8..32, occupancy 43..77%,
// global gathers +-33%. Floor accounting (295k cyc/CU): VALU 67k + LDS
// random-gather ~80k + TA scattered-global ~50-100k + stores ~20k -- three
// ~25% pipes in series per point-chain. Last untested lever: 2-pt ILP on
// the wave-uniform SINGLE-path structure (R6 only tested it double-path).
// R16 = R15 + 2 points/thread (pl, pl+128), ITERS 8. q>=3: corner-
// interleaved dual gather chains (2x LDS-phase ILP). q<3: sequential (vmcnt
// already pipelined). Transpose: two rounds through the same 16KB buffer
// (LDS 80KB unchanged, 2 blocks/CU). VGPR 28 -> ~55 (hard cap 64 observed
// R12/R13; spill tripwires: FETCH/WRITE must stay 10.3MB/131072KB).

#define BLOCK 1024
#define NBLOCKS 512
#define ITERS 8             // 256 points per block-iter; 512*8*256 = 1048576
#define STAGED_ROWS 16382   // levels 0..12: sum 2^(l+1) = 2^14-2
#define TBL_LDS_BYTES 65536
#define LDS_BYTES (TBL_LDS_BYTES + 16 * 128 * 8)   // 81920 -> 2 blocks/CU

constexpr unsigned P1 = 2654435761u, P2 = 29675113u, P3 = 123456789u;
constexpr unsigned HA = P1 * P2 * P3;
constexpr unsigned HB = P2 * P3;
constexpr unsigned HC = P3;

// LDS (fp16 half2 rows, 4B): H2[c] = ((h000 + D[c]) << 2) byte offsets.
#define PREP2(PX, PY, PZ, FRES, H2, WARR) \
    unsigned H2[8]; float WARR[8]; { \
        const float csx = ((PX) + 1.0f) * (FRES); \
        const float csy = ((PY) + 1.0f) * (FRES); \
        const float csz = ((PZ) + 1.0f) * (FRES); \
        const float cfx = floorf(csx), cfy = floorf(csy), cfz = floorf(csz); \
        const float tx = csx - cfx, ty = csy - cfy, tz = csz - cfz; \
        const unsigned hh = ((unsigned)cfx * HA + (unsigned)cfy * HB + (unsigned)cfz * HC) << 2; \
        const float ux = 1.0f - tx, uy = 1.0f - ty, uz = 1.0f - tz; \
        const float m00 = uy * uz, m10 = ty * uz, m01 = uy * tz, m11 = ty * tz; \
        WARR[0] = ux * m00; WARR[1] = tx * m00; \
        WARR[2] = ux * m10; WARR[3] = tx * m10; \
        WARR[4] = ux * m01; WARR[5] = tx * m01; \
        WARR[6] = ux * m11; WARR[7] = tx * m11; \
        H2[0] = hh;                        H2[1] = hh + (HA << 2); \
        H2[2] = hh + (HB << 2);            H2[3] = hh + ((HA + HB) << 2); \
        H2[4] = hh + (HC << 2);            H2[5] = hh + ((HA + HC) << 2); \
        H2[6] = hh + ((HB + HC) << 2);     H2[7] = hh + ((HA + HB + HC) << 2); \
    }

// Global (fp32 float2 rows, 8B): H3[c] = ((h000 + D[c]) << 3) byte offsets.
#define PREP3(PX, PY, PZ, FRES, H3, WARR) \
    unsigned H3[8]; float WARR[8]; { \
        const float csx = ((PX) + 1.0f) * (FRES); \
        const float csy = ((PY) + 1.0f) * (FRES); \
        const float csz = ((PZ) + 1.0f) * (FRES); \
        const float cfx = floorf(csx), cfy = floorf(csy), cfz = floorf(csz); \
        const float tx = csx - cfx, ty = csy - cfy, tz = csz - cfz; \
        const unsigned hh = ((unsigned)cfx * HA + (unsigned)cfy * HB + (unsigned)cfz * HC) << 3; \
        const float ux = 1.0f - tx, uy = 1.0f - ty, uz = 1.0f - tz; \
        const float m00 = uy * uz, m10 = ty * uz, m01 = uy * tz, m11 = ty * tz; \
        WARR[0] = ux * m00; WARR[1] = tx * m00; \
        WARR[2] = ux * m10; WARR[3] = tx * m10; \
        WARR[4] = ux * m01; WARR[5] = tx * m01; \
        WARR[6] = ux * m11; WARR[7] = tx * m11; \
        H3[0] = hh;                        H3[1] = hh + (HA << 3); \
        H3[2] = hh + (HB << 3);            H3[3] = hh + ((HA + HB) << 3); \
        H3[4] = hh + (HC << 3);            H3[5] = hh + ((HA + HC) << 3); \
        H3[6] = hh + ((HB + HC) << 3);     H3[7] = hh + ((HA + HB + HC) << 3); \
    }

__device__ __forceinline__ float2 h2f(unsigned u) {
    __half2 hh = *(__half2*)&u;
    return __half22float2(hh);
}

// Single-point pair (used sequentially on the q<3 global waves).
template<int LA, int LB>
__device__ __forceinline__ void computePairGb(
    const char* ldsc, const char* gtab,
    float px, float py, float pz, float2& oA, float2& oB)
{
    constexpr unsigned MA2 = ((2u << LA) - 1u) << 2;
    constexpr unsigned OA2 = ((2u << LA) - 2u) << 2;
    constexpr unsigned MB3 = ((2u << LB) - 1u) << 3;
    constexpr unsigned OB3 = ((2u << LB) - 2u) << 3;

    float a0 = 0.0f, a1 = 0.0f, b0 = 0.0f, b1 = 0.0f;

    // Issue 8 global float2 loads first (L2-resident table), run the cheap
    // LDS level in the shadow, accumulate last (late vmcnt).
    PREP3(px, py, pz, 512.0f, h3B, wB)
    const char* gb = gtab + OB3;
    const float2 g0 = *(const float2*)(gb + (h3B[0] & MB3));
    const float2 g1 = *(const float2*)(gb + (h3B[1] & MB3));
    const float2 g2 = *(const float2*)(gb + (h3B[2] & MB3));
    const float2 g3 = *(const float2*)(gb + (h3B[3] & MB3));
    const float2 g4 = *(const float2*)(gb + (h3B[4] & MB3));
    const float2 g5 = *(const float2*)(gb + (h3B[5] & MB3));
    const float2 g6 = *(const float2*)(gb + (h3B[6] & MB3));
    const float2 g7 = *(const float2*)(gb + (h3B[7] & MB3));
    {
        PREP2(px, py, pz, (float)(16 << LA), h2A, wA)
#pragma unroll
        for (int c = 0; c < 8; ++c) {
            float2 f = h2f(*(const unsigned*)(ldsc + OA2 + (h2A[c] & MA2)));
            a0 += f.x * wA[c]; a1 += f.y * wA[c];
        }
    }
    b0 += g0.x * wB[0]; b1 += g0.y * wB[0];
    b0 += g1.x * wB[1]; b1 += g1.y * wB[1];
    b0 += g2.x * wB[2]; b1 += g2.y * wB[2];
    b0 += g3.x * wB[3]; b1 += g3.y * wB[3];
    b0 += g4.x * wB[4]; b1 += g4.y * wB[4];
    b0 += g5.x * wB[5]; b1 += g5.y * wB[5];
    b0 += g6.x * wB[6]; b1 += g6.y * wB[6];
    b0 += g7.x * wB[7]; b1 += g7.y * wB[7];

    oA = make_float2(a0, a1);
    oB = make_float2(b0, b1);
}

// Two points, both levels from LDS, gather chains interleaved corner-wise:
// 2x independent LDS chains in flight per wave.
template<int LA, int LB>
__device__ __forceinline__ void computePair2Lds(
    const char* ldsc,
    float px0, float py0, float pz0,
    float px1, float py1, float pz1,
    float2& oA0, float2& oB0, float2& oA1, float2& oB1)
{
    constexpr unsigned MA2 = ((2u << LA) - 1u) << 2;
    constexpr unsigned OA2 = ((2u << LA) - 2u) << 2;
    constexpr unsigned MB2 = ((2u << LB) - 1u) << 2;
    constexpr unsigned OB2 = ((2u << LB) - 2u) << 2;

    float a00 = 0.0f, a01 = 0.0f, b00 = 0.0f, b01 = 0.0f;
    float a10 = 0.0f, a11 = 0.0f, b10 = 0.0f, b11 = 0.0f;

    if constexpr (LA >= 5) {
        // Both levels res 512: one prep per point, 4 chains interleaved.
        PREP2(px0, py0, pz0, 512.0f, h0, w0)
        PREP2(px1, py1, pz1, 512.0f, h1, w1)
#pragma unroll
        for (int c = 0; c < 8; ++c) {
            float2 fA0 = h2f(*(const unsigned*)(ldsc + OA2 + (h0[c] & MA2)));
            float2 fA1 = h2f(*(const unsigned*)(ldsc + OA2 + (h1[c] & MA2)));
            float2 fB0 = h2f(*(const unsigned*)(ldsc + OB2 + (h0[c] & MB2)));
            float2 fB1 = h2f(*(const unsigned*)(ldsc + OB2 + (h1[c] & MB2)));
            a00 += fA0.x * w0[c]; a01 += fA0.y * w0[c];
            a10 += fA1.x * w1[c]; a11 += fA1.y * w1[c];
            b00 += fB0.x * w0[c]; b01 += fB0.y * w0[c];
            b10 += fB1.x * w1[c]; b11 += fB1.y * w1[c];
        }
    } else {
        // LA in {3,4}: level-A preps (small res), interleaved A chains,
        // then level-B preps (res 512), interleaved B chains.
        {
            PREP2(px0, py0, pz0, (float)(16 << LA), hA0, wA0)
            PREP2(px1, py1, pz1, (float)(16 << LA), hA1, wA1)
#pragma unroll
            for (int c = 0; c < 8; ++c) {
                float2 f0 = h2f(*(const unsigned*)(ldsc + OA2 + (hA0[c] & MA2)));
                float2 f1 = h2f(*(const unsigned*)(ldsc + OA2 + (hA1[c] & MA2)));
                a00 += f0.x * wA0[c]; a01 += f0.y * wA0[c];
                a10 += f1.x * wA1[c]; a11 += f1.y * wA1[c];
            }
        }
        {
            PREP2(px0, py0, pz0, 512.0f, hB0, wB0)
            PREP2(px1, py1, pz1, 512.0f, hB1, wB1)
#pragma unroll
            for (int c = 0; c < 8; ++c) {
                float2 f0 = h2f(*(const unsigned*)(ldsc + OB2 + (hB0[c] & MB2)));
                float2 f1 = h2f(*(const unsigned*)(ldsc + OB2 + (hB1[c] & MB2)));
                b00 += f0.x * wB0[c]; b01 += f0.y * wB0[c];
                b10 += f1.x * wB1[c]; b11 += f1.y * wB1[c];
            }
        }
    }
    oA0 = make_float2(a00, a01);
    oB0 = make_float2(b00, b01);
    oA1 = make_float2(a10, a11);
    oB1 = make_float2(b10, b11);
}

__global__ __launch_bounds__(BLOCK) void ngp_encode_kernel(
    const float* __restrict__ coords,
    const float* __restrict__ table,
    float* __restrict__ out)
{
    extern __shared__ unsigned char lds_raw[];
    const char* ldsc = (const char*)lds_raw;                 // fp16 half2 rows
    float2* lds_t = (float2*)(lds_raw + TBL_LDS_BYTES);      // [16][128], swizzled

    // ---- stage levels 0..12 as fp16 (float4 = 2 rows) ----
    {
        const float4* __restrict__ t4 = (const float4*)table;
        uint2* __restrict__ l2 = (uint2*)lds_raw;
        for (int r = threadIdx.x; r < STAGED_ROWS / 2; r += BLOCK) {  // 8191
            float4 v = t4[r];
            __half2 a = __floats2half2_rn(v.x, v.y);
            __half2 b = __floats2half2_rn(v.z, v.w);
            uint2 u;
            u.x = *(unsigned*)&a;
            u.y = *(unsigned*)&b;
            l2[r] = u;
        }
    }
    __syncthreads();

    const char* gtab = (const char*)table;
    float4* __restrict__ out4 = (float4*)out;

    // Wave-uniform level assignment: wave q owns levels (q, 15-q).
    const int wv   = __builtin_amdgcn_readfirstlane((int)(threadIdx.x >> 6));
    const int q    = wv & 7;
    const int g    = wv >> 3;           // point-group 0/1
    const int lane = threadIdx.x & 63;
    const int pl   = g * 64 + lane;     // local point 0..127 within round

    const int lA = q;
    const int lB = 15 - q;
    const unsigned xA = (unsigned)(lA & 14), xB = (unsigned)(lB & 14);

    // Prologue: coords for iter 0 (points pl and pl+128).
    {
        const int pb0 = blockIdx.x * (ITERS * 256);
        // nothing else
    }
    int pfirst = blockIdx.x * (ITERS * 256) + pl;
    float cx0 = coords[3 * pfirst + 0];
    float cy0 = coords[3 * pfirst + 1];
    float cz0 = coords[3 * pfirst + 2];
    float cx1 = coords[3 * (pfirst + 128) + 0];
    float cy1 = coords[3 * (pfirst + 128) + 1];
    float cz1 = coords[3 * (pfirst + 128) + 2];

    for (int it = 0; it < ITERS; ++it) {
        const int pbase = blockIdx.x * (ITERS * 256) + it * 256;

        const float px0 = cx0, py0 = cy0, pz0 = cz0;
        const float px1 = cx1, py1 = cy1, pz1 = cz1;

        // Prefetch next iter's coords: vmcnt lands ~4 barriers later.
        if (it + 1 < ITERS) {
            const int pn = pbase + 256 + pl;
            cx0 = coords[3 * pn + 0];
            cy0 = coords[3 * pn + 1];
            cz0 = coords[3 * pn + 2];
            cx1 = coords[3 * (pn + 128) + 0];
            cy1 = coords[3 * (pn + 128) + 1];
            cz1 = coords[3 * (pn + 128) + 2];
        }

        float2 oA0, oB0, oA1, oB1;
        switch (q) {
        case 0:
            computePairGb<0, 15>(ldsc, gtab, px0, py0, pz0, oA0, oB0);
            computePairGb<0, 15>(ldsc, gtab, px1, py1, pz1, oA1, oB1);
            break;
        case 1:
            computePairGb<1, 14>(ldsc, gtab, px0, py0, pz0, oA0, oB0);
            computePairGb<1, 14>(ldsc, gtab, px1, py1, pz1, oA1, oB1);
            break;
        case 2:
            computePairGb<2, 13>(ldsc, gtab, px0, py0, pz0, oA0, oB0);
            computePairGb<2, 13>(ldsc, gtab, px1, py1, pz1, oA1, oB1);
            break;
        case 3: computePair2Lds<3, 12>(ldsc, px0, py0, pz0, px1, py1, pz1, oA0, oB0, oA1, oB1); break;
        case 4: computePair2Lds<4, 11>(ldsc, px0, py0, pz0, px1, py1, pz1, oA0, oB0, oA1, oB1); break;
        case 5: computePair2Lds<5, 10>(ldsc, px0, py0, pz0, px1, py1, pz1, oA0, oB0, oA1, oB1); break;
        case 6: computePair2Lds<6,  9>(ldsc, px0, py0, pz0, px1, py1, pz1, oA0, oB0, oA1, oB1); break;
        default: computePair2Lds<7, 8>(ldsc, px0, py0, pz0, px1, py1, pz1, oA0, oB0, oA1, oB1); break;
        }

        // ---- transpose round A: points pbase..pbase+127 ----
        lds_t[lA * 128 + (pl ^ xA)] = oA0;
        lds_t[lB * 128 + (pl ^ xB)] = oB0;
        __syncthreads();
        {
            const int j  = threadIdx.x;
            const int lp = j >> 3, qq = j & 7;
            float2 a = lds_t[(2 * qq + 0) * 128 + (lp ^ (2 * qq))];
            float2 b = lds_t[(2 * qq + 1) * 128 + (lp ^ (2 * qq))];
            out4[(size_t)pbase * 8 + j] = make_float4(a.x, a.y, b.x, b.y);
        }
        __syncthreads();

        // ---- transpose round B: points pbase+128..pbase+255 ----
        lds_t[lA * 128 + (pl ^ xA)] = oA1;
        lds_t[lB * 128 + (pl ^ xB)] = oB1;
        __syncthreads();
        {
            const int j  = threadIdx.x;
            const int lp = j >> 3, qq = j & 7;
            float2 a = lds_t[(2 * qq + 0) * 128 + (lp ^ (2 * qq))];
            float2 b = lds_t[(2 * qq + 1) * 128 + (lp ^ (2 * qq))];
            out4[(size_t)(pbase + 128) * 8 + j] = make_float4(a.x, a.y, b.x, b.y);
        }
        __syncthreads();
    }
}

extern "C" void kernel_launch(void* const* d_in, const int* in_sizes, int n_in,
                              void* d_out, int out_size, void* d_ws, size_t ws_size,
                              hipStream_t stream) {
    const float* coords = (const float*)d_in[0];
    const float* table  = (const float*)d_in[1];
    float* out = (float*)d_out;

    hipFuncSetAttribute((const void*)ngp_encode_kernel,
                        hipFuncAttributeMaxDynamicSharedMemorySize,
                        LDS_BYTES);

    ngp_encode_kernel<<<NBLOCKS, BLOCK, LDS_BYTES, stream>>>(coords, table, out);
}